// Round 2
// baseline (11064.627 us; speedup 1.0000x reference)
//
#include <hip/hip_runtime.h>
#include <cstdint>
#include <cstdio>

// ---------------- device helpers ----------------

struct Coords { int xi, yi, zi; };

// EXACT replication of reference quantization:
//   idx = (col - lim0) / (lim1 - lim0) * float(size)  (all f32 ops, truncating cast)
// NOTE: no fma contraction possible here (sub, div, mul), so int results are exact.
__device__ __forceinline__ Coords quantc(float x, float y, float z, float sx, float sy, float sz) {
    Coords c;
    c.xi = (int)(((x - 0.0f)    / 51.2f) * sx);
    c.yi = (int)(((y + 25.6f)   / 51.2f) * sy);
    c.zi = (int)(((z + 2.0f)    / 6.4f)  * sz);
    return c;
}

__device__ __forceinline__ int batch_of(int i, const int* __restrict__ ind, int B) {
    int bt = 0;
    for (int b = 1; b < B; ++b) if (i >= ind[b]) bt = b;
    return bt;
}

// VFE per-point features for one scale.
// x[16] = (feat@W.T + b) * (mean@Ww.T + wb);  mean6 out = [mm, gmm]
__device__ __forceinline__ void compute_x16(
    float px, float py, float pz, float pw,
    float mx_, float my_, float mz_, Coords c,
    const float* __restrict__ W, const float* __restrict__ Bv,
    const float* __restrict__ Ww, const float* __restrict__ Wb,
    float* __restrict__ x, float* __restrict__ mean6) {
    float gx = px - (((float)c.xi + 0.5f) * 0.2f + 0.0f);
    float gy = py - (((float)c.yi + 0.5f) * 0.2f + (-25.6f));
    float gz = pz - (((float)c.zi + 0.5f) * 0.2f + (-2.0f));
    float mmx = px - mx_, mmy = py - my_, mmz = pz - mz_;
    float feat[10] = {px, py, pz, pw, mmx, mmy, mmz, gx, gy, gz};
    float mean[6]  = {mmx, mmy, mmz, gx, gy, gz};
#pragma unroll
    for (int j = 0; j < 6; ++j) mean6[j] = mean[j];
#pragma unroll
    for (int o = 0; o < 16; ++o) {
        float a = Bv[o];
#pragma unroll
        for (int j = 0; j < 10; ++j) a += feat[j] * W[o * 10 + j];
        float g = Wb[o];
#pragma unroll
        for (int j = 0; j < 6; ++j) g += mean[j] * Ww[o * 6 + j];
        x[o] = a * g;
    }
}

// ---------------- bitmask unique-rank machinery ----------------

// P1: mark occupied voxels in bitmasks (both scales)
__global__ __launch_bounds__(256) void k_bits(
    const float4* __restrict__ pc, const int* __restrict__ ind, int B, int n,
    unsigned* __restrict__ mask05, unsigned* __restrict__ mask1) {
    int i = blockIdx.x * 256 + threadIdx.x;
    if (i >= n) return;
    float4 p = pc[i];
    int bt = batch_of(i, ind, B);
    Coords c05 = quantc(p.x, p.y, p.z, 512.f, 512.f, 64.f);
    Coords c1  = quantc(p.x, p.y, p.z, 256.f, 256.f, 32.f);
    int lid05 = ((bt * 512 + c05.xi) * 512 + c05.yi) * 64 + c05.zi;
    int lid1  = ((bt * 256 + c1.xi)  * 256 + c1.yi)  * 32 + c1.zi;
    atomicOr(&mask05[lid05 >> 5], 1u << (lid05 & 31));
    atomicOr(&mask1[lid1 >> 5],  1u << (lid1 & 31));
}

// per-2048-word chunk popcount sums
__global__ __launch_bounds__(256) void k_chunk(
    const unsigned* __restrict__ mask, unsigned* __restrict__ bsum, int nWords) {
    int t = threadIdx.x;
    int base = blockIdx.x * 2048 + t;
    unsigned tot = 0;
#pragma unroll
    for (int k = 0; k < 8; ++k) {
        int w = base + k * 256;
        if (w < nWords) tot += __popc(mask[w]);
    }
    __shared__ unsigned s[256];
    s[t] = tot;
    __syncthreads();
    for (int off = 128; off > 0; off >>= 1) {
        if (t < off) s[t] += s[t + off];
        __syncthreads();
    }
    if (t == 0) bsum[blockIdx.x] = s[0];
}

// per-2048-elem chunk raw sums (for u32 count scans)
__global__ __launch_bounds__(256) void k_chunku(
    const unsigned* __restrict__ val, unsigned* __restrict__ bsum, int nElem) {
    int t = threadIdx.x;
    int base = blockIdx.x * 2048 + t;
    unsigned tot = 0;
#pragma unroll
    for (int k = 0; k < 8; ++k) {
        int w = base + k * 256;
        if (w < nElem) tot += val[w];
    }
    __shared__ unsigned s[256];
    s[t] = tot;
    __syncthreads();
    for (int off = 128; off > 0; off >>= 1) {
        if (t < off) s[t] += s[t + off];
        __syncthreads();
    }
    if (t == 0) bsum[blockIdx.x] = s[0];
}

// single-block exclusive scan of chunk sums
__global__ __launch_bounds__(1024) void k_scan(
    const unsigned* __restrict__ bsum, unsigned* __restrict__ bpref,
    unsigned* __restrict__ Uout, int nB) {
    __shared__ unsigned s[1024];
    int t = threadIdx.x;
    int ipt = (nB + 1023) >> 10;
    unsigned tot = 0;
    for (int k = 0; k < ipt; ++k) {
        int e = t * ipt + k;
        if (e < nB) tot += bsum[e];
    }
    s[t] = tot;
    __syncthreads();
    for (int off = 1; off < 1024; off <<= 1) {
        unsigned v = 0;
        if (t >= off) v = s[t - off];
        __syncthreads();
        if (t >= off) s[t] += v;
        __syncthreads();
    }
    unsigned run = s[t] - tot;  // exclusive
    for (int k = 0; k < ipt; ++k) {
        int e = t * ipt + k;
        if (e < nB) { bpref[e] = run; run += bsum[e]; }
    }
    if (t == 1023 && Uout) *Uout = s[1023];
}

// per-word exclusive popcount prefix
__global__ __launch_bounds__(256) void k_wpref(
    const unsigned* __restrict__ mask, const unsigned* __restrict__ bpref,
    unsigned* __restrict__ wpref, int nWords) {
    int t = threadIdx.x;
    int base = blockIdx.x * 2048 + t * 8;
    unsigned p[8];
    unsigned tot = 0;
#pragma unroll
    for (int k = 0; k < 8; ++k) {
        int w = base + k;
        p[k] = (w < nWords) ? __popc(mask[w]) : 0u;
        tot += p[k];
    }
    __shared__ unsigned s[256];
    s[t] = tot;
    __syncthreads();
    for (int off = 1; off < 256; off <<= 1) {
        unsigned v = 0;
        if (t >= off) v = s[t - off];
        __syncthreads();
        if (t >= off) s[t] += v;
        __syncthreads();
    }
    unsigned run = bpref[blockIdx.x] + (s[t] - tot);
#pragma unroll
    for (int k = 0; k < 8; ++k) {
        int w = base + k;
        if (w < nWords) { wpref[w] = run; run += p[k]; }
    }
}

// per-element exclusive value prefix (for u32 count scans) -> start offsets
__global__ __launch_bounds__(256) void k_eprefu(
    const unsigned* __restrict__ val, const unsigned* __restrict__ bpref,
    unsigned* __restrict__ epref, int nElem) {
    int t = threadIdx.x;
    int base = blockIdx.x * 2048 + t * 8;
    unsigned p[8];
    unsigned tot = 0;
#pragma unroll
    for (int k = 0; k < 8; ++k) {
        int w = base + k;
        p[k] = (w < nElem) ? val[w] : 0u;
        tot += p[k];
    }
    __shared__ unsigned s[256];
    s[t] = tot;
    __syncthreads();
    for (int off = 1; off < 256; off <<= 1) {
        unsigned v = 0;
        if (t >= off) v = s[t - off];
        __syncthreads();
        if (t >= off) s[t] += v;
        __syncthreads();
    }
    unsigned run = bpref[blockIdx.x] + (s[t] - tot);
#pragma unroll
    for (int k = 0; k < 8; ++k) {
        int w = base + k;
        if (w < nElem) { epref[w] = run; run += p[k]; }
    }
}

// ---------------- point passes ----------------

// ranks per point + per-voxel counts (atomicAdd return value = within-segment slot)
__global__ __launch_bounds__(256) void k_rank(
    const float4* __restrict__ pc, const int* __restrict__ ind, int B, int n,
    const unsigned* __restrict__ mask05, const unsigned* __restrict__ wp05,
    const unsigned* __restrict__ mask1, const unsigned* __restrict__ wp1,
    unsigned* __restrict__ inv05, unsigned* __restrict__ inv1,
    unsigned* __restrict__ cnt05, unsigned* __restrict__ cnt1,
    unsigned* __restrict__ slot05, unsigned* __restrict__ slot1,
    float* __restrict__ outCoord, float* __restrict__ outInv) {
    int i = blockIdx.x * 256 + threadIdx.x;
    if (i >= n) return;
    float4 p = pc[i];
    int bt = batch_of(i, ind, B);
    Coords c05 = quantc(p.x, p.y, p.z, 512.f, 512.f, 64.f);
    Coords c1  = quantc(p.x, p.y, p.z, 256.f, 256.f, 32.f);
    int lid05 = ((bt * 512 + c05.xi) * 512 + c05.yi) * 64 + c05.zi;
    int lid1  = ((bt * 256 + c1.xi)  * 256 + c1.yi)  * 32 + c1.zi;

    unsigned w = (unsigned)lid05 >> 5, b = (unsigned)lid05 & 31u;
    unsigned r05 = wp05[w] + __popc(mask05[w] & ((1u << b) - 1u));
    w = (unsigned)lid1 >> 5; b = (unsigned)lid1 & 31u;
    unsigned r1 = wp1[w] + __popc(mask1[w] & ((1u << b) - 1u));

    inv05[i] = r05;
    inv1[i] = r1;
    outInv[i] = (float)r1;
    ((float4*)outCoord)[r1] = make_float4((float)bt, (float)c1.xi, (float)c1.yi, (float)c1.zi);

    slot05[i] = atomicAdd(&cnt05[r05], 1u);
    slot1[i]  = atomicAdd(&cnt1[r1], 1u);
}

// scatter point indices into CSR order (no atomics — slot precomputed)
__global__ __launch_bounds__(256) void k_slot(
    const unsigned* __restrict__ inv05, const unsigned* __restrict__ inv1,
    const unsigned* __restrict__ slot05, const unsigned* __restrict__ slot1,
    const unsigned* __restrict__ start05, const unsigned* __restrict__ start1,
    unsigned* __restrict__ order05, unsigned* __restrict__ order1, int n) {
    int i = blockIdx.x * 256 + threadIdx.x;
    if (i >= n) return;
    order05[start05[inv05[i]] + slot05[i]] = i;
    order1[start1[inv1[i]] + slot1[i]] = i;
}

// one thread per scale-0.5 voxel: mean + mx05, written once, coalesced-ish
__global__ __launch_bounds__(256) void k_vox05(
    const float4* __restrict__ pc,
    const unsigned* __restrict__ start05, const unsigned* __restrict__ cnt05,
    const unsigned* __restrict__ order05,
    const float* __restrict__ w05, const float* __restrict__ b05,
    const float* __restrict__ ww05, const float* __restrict__ wb05,
    float4* __restrict__ mean05, float* __restrict__ mx05, int n) {
    int v = blockIdx.x * 256 + threadIdx.x;
    if (v >= n) return;
    unsigned c = cnt05[v];
    if (c == 0) return;  // rows >= U05 never read
    unsigned beg = start05[v];
    float sx = 0.f, sy = 0.f, sz = 0.f;
    for (unsigned u = 0; u < c; ++u) {
        float4 p = pc[order05[beg + u]];
        sx += p.x; sy += p.y; sz += p.z;
    }
    float cf = fmaxf((float)c, 1.0f);
    float mx_ = sx / cf, my_ = sy / cf, mz_ = sz / cf;
    float m[16];
#pragma unroll
    for (int o = 0; o < 16; ++o) m[o] = -__builtin_inff();
    for (unsigned u = 0; u < c; ++u) {
        float4 p = pc[order05[beg + u]];
        Coords cc = quantc(p.x, p.y, p.z, 512.f, 512.f, 64.f);
        float x[16], d6[6];
        compute_x16(p.x, p.y, p.z, p.w, mx_, my_, mz_, cc, w05, b05, ww05, wb05, x, d6);
#pragma unroll
        for (int o = 0; o < 16; ++o) m[o] = fmaxf(m[o], x[o]);
    }
    mean05[v] = make_float4(mx_, my_, mz_, 0.f);
    float4* mr = (float4*)(mx05 + (size_t)v * 16);
#pragma unroll
    for (int k = 0; k < 4; ++k) mr[k] = make_float4(m[4*k], m[4*k+1], m[4*k+2], m[4*k+3]);
}

// one thread per scale-1 voxel: mean1 + mx1 (in-register) + full am/at/af pipeline,
// max over points in registers, single coalesced 128B output write. Zero atomics.
__global__ __launch_bounds__(256) void k_vox1(
    const float4* __restrict__ pc,
    const unsigned* __restrict__ start1, const unsigned* __restrict__ cnt1,
    const unsigned* __restrict__ order1,
    const unsigned* __restrict__ inv05,
    const float4* __restrict__ mean05, const float* __restrict__ mx05,
    const float* __restrict__ w05, const float* __restrict__ b05,
    const float* __restrict__ ww05, const float* __restrict__ wb05,
    const float* __restrict__ w1g, const float* __restrict__ b1g,
    const float* __restrict__ ww1, const float* __restrict__ wb1,
    const float* __restrict__ am_w, const float* __restrict__ am_b,
    const float* __restrict__ at_w, const float* __restrict__ at_b,
    const float* __restrict__ af_w, const float* __restrict__ af_b,
    float* __restrict__ outMax, float* __restrict__ outCoord, int n) {
    int v = blockIdx.x * 256 + threadIdx.x;
    if (v >= n) return;
    unsigned c = cnt1[v];
    float4* ov = (float4*)(outMax + (size_t)v * 32);
    if (c == 0) {  // padded rows: zero maxf row + zero coord row
        float4 z = make_float4(0.f, 0.f, 0.f, 0.f);
#pragma unroll
        for (int k = 0; k < 8; ++k) ov[k] = z;
        ((float4*)outCoord)[v] = z;
        return;
    }
    unsigned beg = start1[v];
    // pass 1: voxel mean
    float sx = 0.f, sy = 0.f, sz = 0.f;
    for (unsigned u = 0; u < c; ++u) {
        float4 p = pc[order1[beg + u]];
        sx += p.x; sy += p.y; sz += p.z;
    }
    float cf = fmaxf((float)c, 1.0f);
    float m1x = sx / cf, m1y = sy / cf, m1z = sz / cf;
    // pass 2: mx1 in registers
    float mx1v[16];
#pragma unroll
    for (int o = 0; o < 16; ++o) mx1v[o] = -__builtin_inff();
    for (unsigned u = 0; u < c; ++u) {
        float4 p = pc[order1[beg + u]];
        Coords cc = quantc(p.x, p.y, p.z, 256.f, 256.f, 32.f);
        float x[16], d6[6];
        compute_x16(p.x, p.y, p.z, p.w, m1x, m1y, m1z, cc, w1g, b1g, ww1, wb1, x, d6);
#pragma unroll
        for (int o = 0; o < 16; ++o) mx1v[o] = fmaxf(mx1v[o], x[o]);
    }
    // hoist the mx1 partial dot of `at` (voxel-constant across points)
    float atp[32];
#pragma unroll
    for (int o = 0; o < 32; ++o) {
        float s = at_b[o];
#pragma unroll
        for (int j = 0; j < 16; ++j) s += mx1v[j] * at_w[o * 64 + 48 + j];
        atp[o] = s;
    }
    // pass 3: per-point agg, max in registers
    float acc[32];
#pragma unroll
    for (int o = 0; o < 32; ++o) acc[o] = -__builtin_inff();
    for (unsigned u = 0; u < c; ++u) {
        int pi = (int)order1[beg + u];
        float4 p = pc[pi];
        unsigned r05 = inv05[pi];
        float4 mv = mean05[r05];
        Coords c05 = quantc(p.x, p.y, p.z, 512.f, 512.f, 64.f);
        Coords c1  = quantc(p.x, p.y, p.z, 256.f, 256.f, 32.f);
        float x05[16], d6[6], x1[16], mean6[6];
        compute_x16(p.x, p.y, p.z, p.w, mv.x, mv.y, mv.z, c05, w05, b05, ww05, wb05, x05, d6);
        compute_x16(p.x, p.y, p.z, p.w, m1x, m1y, m1z, c1, w1g, b1g, ww1, wb1, x1, mean6);
        const float4* g4 = (const float4*)(mx05 + (size_t)r05 * 16);
        float g[16];
#pragma unroll
        for (int k = 0; k < 4; ++k) {
            float4 t = g4[k];
            g[4*k] = t.x; g[4*k+1] = t.y; g[4*k+2] = t.z; g[4*k+3] = t.w;
        }
        float h[32];
#pragma unroll
        for (int o = 0; o < 32; ++o) {
            float am = am_b[o];
#pragma unroll
            for (int j = 0; j < 6; ++j) am += mean6[j] * am_w[o * 6 + j];
            float at = atp[o];
#pragma unroll
            for (int j = 0; j < 16; ++j) at += x05[j] * at_w[o * 64 + j];
#pragma unroll
            for (int j = 0; j < 16; ++j) at += g[j] * at_w[o * 64 + 16 + j];
#pragma unroll
            for (int j = 0; j < 16; ++j) at += x1[j] * at_w[o * 64 + 32 + j];
            h[o] = fmaxf(am, 0.f) * fmaxf(at, 0.f);
        }
#pragma unroll
        for (int o = 0; o < 32; ++o) {
            float val = af_b[o];
#pragma unroll
            for (int j = 0; j < 32; ++j) val += h[j] * af_w[o * 32 + j];
            acc[o] = fmaxf(acc[o], val);
        }
    }
#pragma unroll
    for (int k = 0; k < 8; ++k)
        ov[k] = make_float4(acc[4*k], acc[4*k+1], acc[4*k+2], acc[4*k+3]);
}

// ---------------- host launch ----------------

extern "C" void kernel_launch(void* const* d_in, const int* in_sizes, int n_in,
                              void* d_out, int out_size, void* d_ws, size_t ws_size,
                              hipStream_t stream) {
    const float4* pc = (const float4*)d_in[0];
    const int* ind   = (const int*)d_in[1];
    const float* w05 = (const float*)d_in[2];
    const float* b05 = (const float*)d_in[3];
    const float* ww05 = (const float*)d_in[4];
    const float* wb05 = (const float*)d_in[5];
    const float* w1  = (const float*)d_in[6];
    const float* b1  = (const float*)d_in[7];
    const float* ww1 = (const float*)d_in[8];
    const float* wb1 = (const float*)d_in[9];
    const float* am_w = (const float*)d_in[10];
    const float* am_b = (const float*)d_in[11];
    const float* at_w = (const float*)d_in[12];
    const float* at_b = (const float*)d_in[13];
    const float* af_w = (const float*)d_in[14];
    const float* af_b = (const float*)d_in[15];

    int n = in_sizes[0] / 4;
    int B = in_sizes[1] - 1;

    int nW05 = B * (512 * 512 * 64 / 32);  // bitmask words, scale 0.5 (~1.05M for B=2)
    int nW1  = B * (256 * 256 * 32 / 32);  // bitmask words, scale 1  (~131k)
    int nB05 = (nW05 + 2047) / 2048;
    int nB1  = (nW1 + 2047) / 2048;
    int nCh  = (n + 2047) / 2048;          // chunks for count scans

    size_t off = 0;
    char* base = (char*)d_ws;
    auto take = [&](size_t bytes) -> char* {
        char* p = base + off;
        off = (off + bytes + 255) & ~(size_t)255;
        return p;
    };

    // --- zero-initialized group (single memset) ---
    unsigned* mask05 = (unsigned*)take((size_t)nW05 * 4);
    unsigned* mask1  = (unsigned*)take((size_t)nW1 * 4);
    unsigned* cnt05  = (unsigned*)take((size_t)n * 4);
    unsigned* cnt1   = (unsigned*)take((size_t)n * 4);
    size_t zeroBytes = off;

    // --- fully-overwritten group ---
    unsigned* wp05   = (unsigned*)take((size_t)nW05 * 4);
    unsigned* wp1    = (unsigned*)take((size_t)nW1 * 4);
    unsigned* inv05  = (unsigned*)take((size_t)n * 4);
    unsigned* inv1   = (unsigned*)take((size_t)n * 4);
    unsigned* slot05 = (unsigned*)take((size_t)n * 4);
    unsigned* slot1  = (unsigned*)take((size_t)n * 4);
    unsigned* start05 = (unsigned*)take((size_t)n * 4);
    unsigned* start1  = (unsigned*)take((size_t)n * 4);
    unsigned* order05 = (unsigned*)take((size_t)n * 4);
    unsigned* order1  = (unsigned*)take((size_t)n * 4);
    float4*   mean05  = (float4*)take((size_t)n * 16);
    float*    mx05    = (float*)take((size_t)n * 16 * 4);
    unsigned* bsum05  = (unsigned*)take((size_t)nB05 * 4);
    unsigned* bpref05 = (unsigned*)take((size_t)nB05 * 4);
    unsigned* bsum1   = (unsigned*)take((size_t)nB1 * 4);
    unsigned* bpref1  = (unsigned*)take((size_t)nB1 * 4);
    unsigned* bsC05   = (unsigned*)take((size_t)nCh * 4);
    unsigned* bpC05   = (unsigned*)take((size_t)nCh * 4);
    unsigned* bsC1    = (unsigned*)take((size_t)nCh * 4);
    unsigned* bpC1    = (unsigned*)take((size_t)nCh * 4);
    size_t total = off;

    if (ws_size < total) {
        fprintf(stderr, "kernel_launch: ws too small (%zu < %zu)\n", ws_size, total);
        return;
    }

    float* outMaxF = (float*)d_out;                       // [n,32]
    float* outCoord = (float*)d_out + (size_t)n * 32;     // [n,4]
    float* outInv = (float*)d_out + (size_t)n * 36;       // [n]

    hipMemsetAsync(d_ws, 0, zeroBytes, stream);  // masks + counts only (~13 MB)

    int gpts = (n + 255) / 256;
    // unique-rank machinery (bitmask + hierarchical popcount scan)
    k_bits<<<gpts, 256, 0, stream>>>(pc, ind, B, n, mask05, mask1);
    k_chunk<<<nB05, 256, 0, stream>>>(mask05, bsum05, nW05);
    k_chunk<<<nB1, 256, 0, stream>>>(mask1, bsum1, nW1);
    k_scan<<<1, 1024, 0, stream>>>(bsum05, bpref05, nullptr, nB05);
    k_scan<<<1, 1024, 0, stream>>>(bsum1, bpref1, nullptr, nB1);
    k_wpref<<<nB05, 256, 0, stream>>>(mask05, bpref05, wp05, nW05);
    k_wpref<<<nB1, 256, 0, stream>>>(mask1, bpref1, wp1, nW1);
    // ranks + counts (+slots)
    k_rank<<<gpts, 256, 0, stream>>>(pc, ind, B, n, mask05, wp05, mask1, wp1,
                                     inv05, inv1, cnt05, cnt1, slot05, slot1,
                                     outCoord, outInv);
    // exclusive scan of counts -> CSR starts
    k_chunku<<<nCh, 256, 0, stream>>>(cnt05, bsC05, n);
    k_chunku<<<nCh, 256, 0, stream>>>(cnt1, bsC1, n);
    k_scan<<<1, 1024, 0, stream>>>(bsC05, bpC05, nullptr, nCh);
    k_scan<<<1, 1024, 0, stream>>>(bsC1, bpC1, nullptr, nCh);
    k_eprefu<<<nCh, 256, 0, stream>>>(cnt05, bpC05, start05, n);
    k_eprefu<<<nCh, 256, 0, stream>>>(cnt1, bpC1, start1, n);
    // counting-sort scatter (no atomics)
    k_slot<<<gpts, 256, 0, stream>>>(inv05, inv1, slot05, slot1,
                                     start05, start1, order05, order1, n);
    // per-voxel reductions (no atomics, coalesced writes)
    k_vox05<<<gpts, 256, 0, stream>>>(pc, start05, cnt05, order05,
                                      w05, b05, ww05, wb05, mean05, mx05, n);
    k_vox1<<<gpts, 256, 0, stream>>>(pc, start1, cnt1, order1, inv05, mean05, mx05,
                                     w05, b05, ww05, wb05, w1, b1, ww1, wb1,
                                     am_w, am_b, at_w, at_b, af_w, af_b,
                                     outMaxF, outCoord, n);

    (void)n_in; (void)out_size; (void)outMaxF;
}

// Round 3
// 1528.301 us; speedup vs baseline: 7.2398x; 7.2398x over previous
//
#include <hip/hip_runtime.h>
#include <cstdint>
#include <cstdio>

// ---------------- device helpers ----------------

struct Coords { int xi, yi, zi; };

// EXACT replication of reference quantization (all f32 ops, truncating cast)
__device__ __forceinline__ Coords quantc(float x, float y, float z, float sx, float sy, float sz) {
    Coords c;
    c.xi = (int)(((x - 0.0f)  / 51.2f) * sx);
    c.yi = (int)(((y + 25.6f) / 51.2f) * sy);
    c.zi = (int)(((z + 2.0f)  / 6.4f)  * sz);
    return c;
}

__device__ __forceinline__ int batch_of(int i, const int* __restrict__ ind, int B) {
    int bt = 0;
    for (int b = 1; b < B; ++b) if (i >= ind[b]) bt = b;
    return bt;
}

// x[16] = (feat@W.T + b) * (mean@Ww.T + wb);  mean6 out = [mm, gmm]
__device__ __forceinline__ void compute_x16(
    float px, float py, float pz, float pw,
    float mx_, float my_, float mz_, Coords c,
    const float* __restrict__ W, const float* __restrict__ Bv,
    const float* __restrict__ Ww, const float* __restrict__ Wb,
    float* __restrict__ x, float* __restrict__ mean6) {
    float gx = px - (((float)c.xi + 0.5f) * 0.2f + 0.0f);
    float gy = py - (((float)c.yi + 0.5f) * 0.2f + (-25.6f));
    float gz = pz - (((float)c.zi + 0.5f) * 0.2f + (-2.0f));
    float mmx = px - mx_, mmy = py - my_, mmz = pz - mz_;
    float feat[10] = {px, py, pz, pw, mmx, mmy, mmz, gx, gy, gz};
    float mean[6]  = {mmx, mmy, mmz, gx, gy, gz};
#pragma unroll
    for (int j = 0; j < 6; ++j) mean6[j] = mean[j];
#pragma unroll
    for (int o = 0; o < 16; ++o) {
        float a = Bv[o];
#pragma unroll
        for (int j = 0; j < 10; ++j) a += feat[j] * W[o * 10 + j];
        float g = Wb[o];
#pragma unroll
        for (int j = 0; j < 6; ++j) g += mean[j] * Ww[o * 6 + j];
        x[o] = a * g;
    }
}

// ---------------- bitmask unique-rank machinery ----------------

__global__ __launch_bounds__(256) void k_bits(
    const float4* __restrict__ pc, const int* __restrict__ ind, int B, int n,
    unsigned* __restrict__ mask05, unsigned* __restrict__ mask1) {
    int i = blockIdx.x * 256 + threadIdx.x;
    if (i >= n) return;
    float4 p = pc[i];
    int bt = batch_of(i, ind, B);
    Coords c05 = quantc(p.x, p.y, p.z, 512.f, 512.f, 64.f);
    Coords c1  = quantc(p.x, p.y, p.z, 256.f, 256.f, 32.f);
    int lid05 = ((bt * 512 + c05.xi) * 512 + c05.yi) * 64 + c05.zi;
    int lid1  = ((bt * 256 + c1.xi)  * 256 + c1.yi)  * 32 + c1.zi;
    atomicOr(&mask05[lid05 >> 5], 1u << (lid05 & 31));
    atomicOr(&mask1[lid1 >> 5],  1u << (lid1 & 31));
}

__global__ __launch_bounds__(256) void k_chunk(
    const unsigned* __restrict__ mask, unsigned* __restrict__ bsum, int nWords) {
    int t = threadIdx.x;
    int base = blockIdx.x * 2048 + t;
    unsigned tot = 0;
#pragma unroll
    for (int k = 0; k < 8; ++k) {
        int w = base + k * 256;
        if (w < nWords) tot += __popc(mask[w]);
    }
    __shared__ unsigned s[256];
    s[t] = tot;
    __syncthreads();
    for (int off = 128; off > 0; off >>= 1) {
        if (t < off) s[t] += s[t + off];
        __syncthreads();
    }
    if (t == 0) bsum[blockIdx.x] = s[0];
}

__global__ __launch_bounds__(256) void k_chunku(
    const unsigned* __restrict__ val, unsigned* __restrict__ bsum, int nElem) {
    int t = threadIdx.x;
    int base = blockIdx.x * 2048 + t;
    unsigned tot = 0;
#pragma unroll
    for (int k = 0; k < 8; ++k) {
        int w = base + k * 256;
        if (w < nElem) tot += val[w];
    }
    __shared__ unsigned s[256];
    s[t] = tot;
    __syncthreads();
    for (int off = 128; off > 0; off >>= 1) {
        if (t < off) s[t] += s[t + off];
        __syncthreads();
    }
    if (t == 0) bsum[blockIdx.x] = s[0];
}

__global__ __launch_bounds__(1024) void k_scan(
    const unsigned* __restrict__ bsum, unsigned* __restrict__ bpref,
    unsigned* __restrict__ Uout, int nB) {
    __shared__ unsigned s[1024];
    int t = threadIdx.x;
    int ipt = (nB + 1023) >> 10;
    unsigned tot = 0;
    for (int k = 0; k < ipt; ++k) {
        int e = t * ipt + k;
        if (e < nB) tot += bsum[e];
    }
    s[t] = tot;
    __syncthreads();
    for (int off = 1; off < 1024; off <<= 1) {
        unsigned v = 0;
        if (t >= off) v = s[t - off];
        __syncthreads();
        if (t >= off) s[t] += v;
        __syncthreads();
    }
    unsigned run = s[t] - tot;  // exclusive
    for (int k = 0; k < ipt; ++k) {
        int e = t * ipt + k;
        if (e < nB) { bpref[e] = run; run += bsum[e]; }
    }
    if (t == 1023 && Uout) *Uout = s[1023];
}

__global__ __launch_bounds__(256) void k_wpref(
    const unsigned* __restrict__ mask, const unsigned* __restrict__ bpref,
    unsigned* __restrict__ wpref, int nWords) {
    int t = threadIdx.x;
    int base = blockIdx.x * 2048 + t * 8;
    unsigned p[8];
    unsigned tot = 0;
#pragma unroll
    for (int k = 0; k < 8; ++k) {
        int w = base + k;
        p[k] = (w < nWords) ? __popc(mask[w]) : 0u;
        tot += p[k];
    }
    __shared__ unsigned s[256];
    s[t] = tot;
    __syncthreads();
    for (int off = 1; off < 256; off <<= 1) {
        unsigned v = 0;
        if (t >= off) v = s[t - off];
        __syncthreads();
        if (t >= off) s[t] += v;
        __syncthreads();
    }
    unsigned run = bpref[blockIdx.x] + (s[t] - tot);
#pragma unroll
    for (int k = 0; k < 8; ++k) {
        int w = base + k;
        if (w < nWords) { wpref[w] = run; run += p[k]; }
    }
}

__global__ __launch_bounds__(256) void k_eprefu(
    const unsigned* __restrict__ val, const unsigned* __restrict__ bpref,
    unsigned* __restrict__ epref, int nElem) {
    int t = threadIdx.x;
    int base = blockIdx.x * 2048 + t * 8;
    unsigned p[8];
    unsigned tot = 0;
#pragma unroll
    for (int k = 0; k < 8; ++k) {
        int w = base + k;
        p[k] = (w < nElem) ? val[w] : 0u;
        tot += p[k];
    }
    __shared__ unsigned s[256];
    s[t] = tot;
    __syncthreads();
    for (int off = 1; off < 256; off <<= 1) {
        unsigned v = 0;
        if (t >= off) v = s[t - off];
        __syncthreads();
        if (t >= off) s[t] += v;
        __syncthreads();
    }
    unsigned run = bpref[blockIdx.x] + (s[t] - tot);
#pragma unroll
    for (int k = 0; k < 8; ++k) {
        int w = base + k;
        if (w < nElem) { epref[w] = run; run += p[k]; }
    }
}

// ---------------- point passes ----------------

// ranks per point + per-voxel counts (atomicAdd return value = within-segment slot)
__global__ __launch_bounds__(256) void k_rank(
    const float4* __restrict__ pc, const int* __restrict__ ind, int B, int n,
    const unsigned* __restrict__ mask05, const unsigned* __restrict__ wp05,
    const unsigned* __restrict__ mask1, const unsigned* __restrict__ wp1,
    unsigned* __restrict__ inv05, unsigned* __restrict__ inv1,
    unsigned* __restrict__ cnt05, unsigned* __restrict__ cnt1,
    unsigned* __restrict__ slot05, unsigned* __restrict__ slot1,
    float* __restrict__ outCoord, float* __restrict__ outInv) {
    int i = blockIdx.x * 256 + threadIdx.x;
    if (i >= n) return;
    float4 p = pc[i];
    int bt = batch_of(i, ind, B);
    Coords c05 = quantc(p.x, p.y, p.z, 512.f, 512.f, 64.f);
    Coords c1  = quantc(p.x, p.y, p.z, 256.f, 256.f, 32.f);
    int lid05 = ((bt * 512 + c05.xi) * 512 + c05.yi) * 64 + c05.zi;
    int lid1  = ((bt * 256 + c1.xi)  * 256 + c1.yi)  * 32 + c1.zi;

    unsigned w = (unsigned)lid05 >> 5, b = (unsigned)lid05 & 31u;
    unsigned r05 = wp05[w] + __popc(mask05[w] & ((1u << b) - 1u));
    w = (unsigned)lid1 >> 5; b = (unsigned)lid1 & 31u;
    unsigned r1 = wp1[w] + __popc(mask1[w] & ((1u << b) - 1u));

    inv05[i] = r05;
    inv1[i] = r1;
    outInv[i] = (float)r1;
    ((float4*)outCoord)[r1] = make_float4((float)bt, (float)c1.xi, (float)c1.yi, (float)c1.zi);

    slot05[i] = atomicAdd(&cnt05[r05], 1u);
    slot1[i]  = atomicAdd(&cnt1[r1], 1u);
}

// counting-sort scatter of point indices into CSR order (no atomics)
__global__ __launch_bounds__(256) void k_slot(
    const unsigned* __restrict__ inv05, const unsigned* __restrict__ inv1,
    const unsigned* __restrict__ slot05, const unsigned* __restrict__ slot1,
    const unsigned* __restrict__ start05, const unsigned* __restrict__ start1,
    unsigned* __restrict__ order05, unsigned* __restrict__ order1, int n) {
    int i = blockIdx.x * 256 + threadIdx.x;
    if (i >= n) return;
    order05[start05[inv05[i]] + slot05[i]] = i;
    order1[start1[inv1[i]] + slot1[i]] = i;
}

// wave-level segmented suffix-sum of xyz over CSR order -> per-voxel mean (owner writes)
__global__ __launch_bounds__(256) void k_segmean(
    const float4* __restrict__ pc,
    const unsigned* __restrict__ order, const unsigned* __restrict__ inv,
    const unsigned* __restrict__ start, const unsigned* __restrict__ cnt,
    float4* __restrict__ meanOut, int n) {
    int j = blockIdx.x * 256 + threadIdx.x;
    int lane = threadIdx.x & 63;
    bool live = j < n;
    unsigned r = 0xFFFFFFFFu;
    float sx = 0.f, sy = 0.f, sz = 0.f;
    if (live) {
        unsigned pi = order[j];
        float4 p = pc[pi];
        r = inv[pi];
        sx = p.x; sy = p.y; sz = p.z;
    }
#pragma unroll
    for (int d = 1; d < 64; d <<= 1) {
        unsigned rn = (unsigned)__shfl_down((int)r, d);
        float ax = __shfl_down(sx, d);
        float ay = __shfl_down(sy, d);
        float az = __shfl_down(sz, d);
        bool ok = (lane + d) < 64 && rn == r;
        if (ok) { sx += ax; sy += ay; sz += az; }
    }
    if (!live) return;
    if (j != (int)start[r]) return;  // owner only
    unsigned c = cnt[r];
    unsigned end = j + c;
    unsigned waveEnd = ((unsigned)j & ~63u) + 64u;
    for (unsigned j2 = waveEnd; j2 < end; ++j2) {  // rare cross-wave overflow
        float4 q = pc[order[j2]];
        sx += q.x; sy += q.y; sz += q.z;
    }
    float cf = (float)c;
    meanOut[r] = make_float4(sx / cf, sy / cf, sz / cf, 0.f);
}

// block-level LDS segmented max of x16 over CSR order -> per-voxel mx (owner writes)
__global__ __launch_bounds__(256) void k_segmx(
    const float4* __restrict__ pc,
    const unsigned* __restrict__ order, const unsigned* __restrict__ inv,
    const unsigned* __restrict__ start, const unsigned* __restrict__ cnt,
    const float4* __restrict__ meanIn,
    const float* __restrict__ W, const float* __restrict__ Bv,
    const float* __restrict__ Ww, const float* __restrict__ Wb,
    float sx_, float sy_, float sz_,          // quant sizes for this scale
    float* __restrict__ mxOut, int n) {
    __shared__ float buf[256][17];
    int t = threadIdx.x;
    int j = blockIdx.x * 256 + t;
    bool live = j < n;
    unsigned r = 0;
    float x[16], d6[6];
    if (live) {
        unsigned pi = order[j];
        float4 p = pc[pi];
        r = inv[pi];
        float4 mv = meanIn[r];
        Coords cc = quantc(p.x, p.y, p.z, sx_, sy_, sz_);
        compute_x16(p.x, p.y, p.z, p.w, mv.x, mv.y, mv.z, cc, W, Bv, Ww, Wb, x, d6);
    } else {
#pragma unroll
        for (int o = 0; o < 16; ++o) x[o] = 0.f;
    }
#pragma unroll
    for (int o = 0; o < 16; ++o) buf[t][o] = x[o];
    __syncthreads();
    if (!live || j != (int)start[r]) return;  // owner only
    unsigned c = cnt[r];
    unsigned end = j + c;
    unsigned blockEnd = ((unsigned)blockIdx.x + 1u) * 256u;
    unsigned inEnd = end < blockEnd ? end : blockEnd;
    for (unsigned j2 = j + 1; j2 < inEnd; ++j2) {
        int t2 = (int)(j2 - (unsigned)blockIdx.x * 256u);
#pragma unroll
        for (int o = 0; o < 16; ++o) x[o] = fmaxf(x[o], buf[t2][o]);
    }
    float4 mv = meanIn[r];
    for (unsigned j2 = blockEnd; j2 < end; ++j2) {  // rare cross-block overflow
        float4 q = pc[order[j2]];
        Coords cc = quantc(q.x, q.y, q.z, sx_, sy_, sz_);
        float x2[16];
        compute_x16(q.x, q.y, q.z, q.w, mv.x, mv.y, mv.z, cc, W, Bv, Ww, Wb, x2, d6);
#pragma unroll
        for (int o = 0; o < 16; ++o) x[o] = fmaxf(x[o], x2[o]);
    }
    float4* mr = (float4*)(mxOut + (size_t)r * 16);
#pragma unroll
    for (int k = 0; k < 4; ++k) mr[k] = make_float4(x[4*k], x[4*k+1], x[4*k+2], x[4*k+3]);
}

// full per-point pipeline value val[32]
__device__ __forceinline__ void agg_point(
    float4 p, unsigned r05,
    const float4* __restrict__ mean05, const float* __restrict__ mx05,
    float4 m1, const float* __restrict__ atp,
    const float* __restrict__ w05, const float* __restrict__ b05,
    const float* __restrict__ ww05, const float* __restrict__ wb05,
    const float* __restrict__ w1g, const float* __restrict__ b1g,
    const float* __restrict__ ww1, const float* __restrict__ wb1,
    const float* __restrict__ am_w, const float* __restrict__ am_b,
    const float* __restrict__ at_w,
    const float* __restrict__ af_w, const float* __restrict__ af_b,
    float* __restrict__ val) {
    float4 mv = mean05[r05];
    Coords c05 = quantc(p.x, p.y, p.z, 512.f, 512.f, 64.f);
    Coords c1  = quantc(p.x, p.y, p.z, 256.f, 256.f, 32.f);
    float x05[16], d6[6], x1[16], mean6[6];
    compute_x16(p.x, p.y, p.z, p.w, mv.x, mv.y, mv.z, c05, w05, b05, ww05, wb05, x05, d6);
    compute_x16(p.x, p.y, p.z, p.w, m1.x, m1.y, m1.z, c1, w1g, b1g, ww1, wb1, x1, mean6);
    float g[16];
    const float4* g4 = (const float4*)(mx05 + (size_t)r05 * 16);
#pragma unroll
    for (int k = 0; k < 4; ++k) {
        float4 tt = g4[k];
        g[4*k] = tt.x; g[4*k+1] = tt.y; g[4*k+2] = tt.z; g[4*k+3] = tt.w;
    }
    float h[32];
#pragma unroll
    for (int o = 0; o < 32; ++o) {
        float am = am_b[o];
#pragma unroll
        for (int jj = 0; jj < 6; ++jj) am += mean6[jj] * am_w[o * 6 + jj];
        float at = atp[o];
#pragma unroll
        for (int jj = 0; jj < 16; ++jj) at += x05[jj] * at_w[o * 64 + jj];
#pragma unroll
        for (int jj = 0; jj < 16; ++jj) at += g[jj] * at_w[o * 64 + 16 + jj];
#pragma unroll
        for (int jj = 0; jj < 16; ++jj) at += x1[jj] * at_w[o * 64 + 32 + jj];
        h[o] = fmaxf(am, 0.f) * fmaxf(at, 0.f);
    }
#pragma unroll
    for (int o = 0; o < 32; ++o) {
        float v = af_b[o];
#pragma unroll
        for (int jj = 0; jj < 32; ++jj) v += h[jj] * af_w[o * 32 + jj];
        val[o] = v;
    }
}

// per-point agg + block-level LDS segmented max -> owner writes d_out row. Zero atomics.
__global__ __launch_bounds__(256) void k_agg2(
    const float4* __restrict__ pc,
    const unsigned* __restrict__ order1, const unsigned* __restrict__ inv1,
    const unsigned* __restrict__ inv05,
    const unsigned* __restrict__ start1, const unsigned* __restrict__ cnt1,
    const float4* __restrict__ mean05, const float* __restrict__ mx05,
    const float4* __restrict__ mean1, const float* __restrict__ mx1,
    const float* __restrict__ w05, const float* __restrict__ b05,
    const float* __restrict__ ww05, const float* __restrict__ wb05,
    const float* __restrict__ w1g, const float* __restrict__ b1g,
    const float* __restrict__ ww1, const float* __restrict__ wb1,
    const float* __restrict__ am_w, const float* __restrict__ am_b,
    const float* __restrict__ at_w, const float* __restrict__ at_b,
    const float* __restrict__ af_w, const float* __restrict__ af_b,
    float* __restrict__ outMax, int n) {
    __shared__ float buf[256][33];
    int t = threadIdx.x;
    int j = blockIdx.x * 256 + t;
    bool live = j < n;
    unsigned r = 0;
    float val[32];
    float4 m1 = make_float4(0.f, 0.f, 0.f, 0.f);
    float atp[32];
    if (live) {
        unsigned pi = order1[j];
        float4 p = pc[pi];
        r = inv1[pi];
        unsigned r05 = inv05[pi];
        m1 = mean1[r];
        // atp = at_b + mx1[r] . at_w[:, 48:64]  (segment-constant partial dot)
        float mxv[16];
        const float4* m4 = (const float4*)(mx1 + (size_t)r * 16);
#pragma unroll
        for (int k = 0; k < 4; ++k) {
            float4 tt = m4[k];
            mxv[4*k] = tt.x; mxv[4*k+1] = tt.y; mxv[4*k+2] = tt.z; mxv[4*k+3] = tt.w;
        }
#pragma unroll
        for (int o = 0; o < 32; ++o) {
            float s = at_b[o];
#pragma unroll
            for (int jj = 0; jj < 16; ++jj) s += mxv[jj] * at_w[o * 64 + 48 + jj];
            atp[o] = s;
        }
        agg_point(p, r05, mean05, mx05, m1, atp,
                  w05, b05, ww05, wb05, w1g, b1g, ww1, wb1,
                  am_w, am_b, at_w, af_w, af_b, val);
    } else {
#pragma unroll
        for (int o = 0; o < 32; ++o) val[o] = 0.f;
    }
#pragma unroll
    for (int o = 0; o < 32; ++o) buf[t][o] = val[o];
    __syncthreads();
    if (!live || j != (int)start1[r]) return;  // owner only
    unsigned c = cnt1[r];
    unsigned end = j + c;
    unsigned blockEnd = ((unsigned)blockIdx.x + 1u) * 256u;
    unsigned inEnd = end < blockEnd ? end : blockEnd;
    for (unsigned j2 = j + 1; j2 < inEnd; ++j2) {
        int t2 = (int)(j2 - (unsigned)blockIdx.x * 256u);
#pragma unroll
        for (int o = 0; o < 32; ++o) val[o] = fmaxf(val[o], buf[t2][o]);
    }
    for (unsigned j2 = blockEnd; j2 < end; ++j2) {  // rare cross-block overflow
        unsigned pi2 = order1[j2];
        float4 p2 = pc[pi2];
        unsigned r052 = inv05[pi2];
        float v2[32];
        agg_point(p2, r052, mean05, mx05, m1, atp,
                  w05, b05, ww05, wb05, w1g, b1g, ww1, wb1,
                  am_w, am_b, at_w, af_w, af_b, v2);
#pragma unroll
        for (int o = 0; o < 32; ++o) val[o] = fmaxf(val[o], v2[o]);
    }
    float4* ov = (float4*)(outMax + (size_t)r * 32);
#pragma unroll
    for (int k = 0; k < 8; ++k)
        ov[k] = make_float4(val[4*k], val[4*k+1], val[4*k+2], val[4*k+3]);
}

// zero maxf + coord rows >= U1
__global__ __launch_bounds__(256) void k_pad(
    float* __restrict__ outMax, float* __restrict__ outCoord,
    const unsigned* __restrict__ U1p, int n) {
    int v = blockIdx.x * 256 + threadIdx.x;
    if (v >= n) return;
    unsigned U = *U1p;
    if ((unsigned)v < U) return;
    float4 z = make_float4(0.f, 0.f, 0.f, 0.f);
    float4* ov = (float4*)(outMax + (size_t)v * 32);
#pragma unroll
    for (int k = 0; k < 8; ++k) ov[k] = z;
    ((float4*)outCoord)[v] = z;
}

// ---------------- host launch ----------------

extern "C" void kernel_launch(void* const* d_in, const int* in_sizes, int n_in,
                              void* d_out, int out_size, void* d_ws, size_t ws_size,
                              hipStream_t stream) {
    const float4* pc = (const float4*)d_in[0];
    const int* ind   = (const int*)d_in[1];
    const float* w05 = (const float*)d_in[2];
    const float* b05 = (const float*)d_in[3];
    const float* ww05 = (const float*)d_in[4];
    const float* wb05 = (const float*)d_in[5];
    const float* w1  = (const float*)d_in[6];
    const float* b1  = (const float*)d_in[7];
    const float* ww1 = (const float*)d_in[8];
    const float* wb1 = (const float*)d_in[9];
    const float* am_w = (const float*)d_in[10];
    const float* am_b = (const float*)d_in[11];
    const float* at_w = (const float*)d_in[12];
    const float* at_b = (const float*)d_in[13];
    const float* af_w = (const float*)d_in[14];
    const float* af_b = (const float*)d_in[15];

    int n = in_sizes[0] / 4;
    int B = in_sizes[1] - 1;

    int nW05 = B * (512 * 512 * 64 / 32);
    int nW1  = B * (256 * 256 * 32 / 32);
    int nB05 = (nW05 + 2047) / 2048;
    int nB1  = (nW1 + 2047) / 2048;
    int nCh  = (n + 2047) / 2048;

    size_t off = 0;
    char* base = (char*)d_ws;
    auto take = [&](size_t bytes) -> char* {
        char* p = base + off;
        off = (off + bytes + 255) & ~(size_t)255;
        return p;
    };

    // ---- persistent region (live through k_agg2/k_pad) ----
    unsigned* inv05  = (unsigned*)take((size_t)n * 4);
    unsigned* inv1   = (unsigned*)take((size_t)n * 4);
    unsigned* start1 = (unsigned*)take((size_t)n * 4);
    unsigned* cnt1   = (unsigned*)take((size_t)n * 4);
    unsigned* order1 = (unsigned*)take((size_t)n * 4);
    float4*   mean05 = (float4*)take((size_t)n * 16);
    float*    mx05   = (float*)take((size_t)n * 64);
    unsigned* U1p    = (unsigned*)take(4);
    size_t tbase = off;

    // ---- transient A (dead before k_segmean(scale1)) ----
    unsigned* mask05 = (unsigned*)take((size_t)nW05 * 4);
    unsigned* mask1  = (unsigned*)take((size_t)nW1 * 4);
    size_t maskBytes = (char*)(mask1 + nW1) - (char*)mask05;
    unsigned* wp05   = (unsigned*)take((size_t)nW05 * 4);
    unsigned* wp1    = (unsigned*)take((size_t)nW1 * 4);
    unsigned* slot05 = (unsigned*)take((size_t)n * 4);
    unsigned* slot1  = (unsigned*)take((size_t)n * 4);
    unsigned* cnt05  = (unsigned*)take((size_t)n * 4);
    unsigned* start05 = (unsigned*)take((size_t)n * 4);
    unsigned* order05 = (unsigned*)take((size_t)n * 4);
    unsigned* bsum05  = (unsigned*)take((size_t)nB05 * 4);
    unsigned* bpref05 = (unsigned*)take((size_t)nB05 * 4);
    unsigned* bsum1   = (unsigned*)take((size_t)nB1 * 4);
    unsigned* bpref1  = (unsigned*)take((size_t)nB1 * 4);
    unsigned* bsC05   = (unsigned*)take((size_t)nCh * 4);
    unsigned* bpC05   = (unsigned*)take((size_t)nCh * 4);
    unsigned* bsC1    = (unsigned*)take((size_t)nCh * 4);
    unsigned* bpC1    = (unsigned*)take((size_t)nCh * 4);
    size_t endA = off;

    // ---- transient B (overlaps A; born at k_segmean(scale1)) ----
    off = tbase;
    float4* mean1 = (float4*)take((size_t)n * 16);
    float*  mx1   = (float*)take((size_t)n * 64);
    size_t endB = off;

    size_t total = endA > endB ? endA : endB;
    if (ws_size < total) {
        fprintf(stderr, "kernel_launch: ws too small (%zu < %zu)\n", ws_size, total);
        return;
    }

    float* outMaxF = (float*)d_out;                      // [n,32]
    float* outCoord = (float*)d_out + (size_t)n * 32;    // [n,4]
    float* outInv = (float*)d_out + (size_t)n * 36;      // [n]

    hipMemsetAsync(mask05, 0, maskBytes, stream);
    hipMemsetAsync(cnt05, 0, (size_t)n * 4, stream);
    hipMemsetAsync(cnt1, 0, (size_t)n * 4, stream);

    int gpts = (n + 255) / 256;
    // unique-rank machinery
    k_bits<<<gpts, 256, 0, stream>>>(pc, ind, B, n, mask05, mask1);
    k_chunk<<<nB05, 256, 0, stream>>>(mask05, bsum05, nW05);
    k_chunk<<<nB1, 256, 0, stream>>>(mask1, bsum1, nW1);
    k_scan<<<1, 1024, 0, stream>>>(bsum05, bpref05, nullptr, nB05);
    k_scan<<<1, 1024, 0, stream>>>(bsum1, bpref1, U1p, nB1);
    k_wpref<<<nB05, 256, 0, stream>>>(mask05, bpref05, wp05, nW05);
    k_wpref<<<nB1, 256, 0, stream>>>(mask1, bpref1, wp1, nW1);
    // ranks + counts + slots
    k_rank<<<gpts, 256, 0, stream>>>(pc, ind, B, n, mask05, wp05, mask1, wp1,
                                     inv05, inv1, cnt05, cnt1, slot05, slot1,
                                     outCoord, outInv);
    // CSR starts
    k_chunku<<<nCh, 256, 0, stream>>>(cnt05, bsC05, n);
    k_chunku<<<nCh, 256, 0, stream>>>(cnt1, bsC1, n);
    k_scan<<<1, 1024, 0, stream>>>(bsC05, bpC05, nullptr, nCh);
    k_scan<<<1, 1024, 0, stream>>>(bsC1, bpC1, nullptr, nCh);
    k_eprefu<<<nCh, 256, 0, stream>>>(cnt05, bpC05, start05, n);
    k_eprefu<<<nCh, 256, 0, stream>>>(cnt1, bpC1, start1, n);
    // counting-sort scatter
    k_slot<<<gpts, 256, 0, stream>>>(inv05, inv1, slot05, slot1,
                                     start05, start1, order05, order1, n);
    // scale-0.5: mean + mx  (uses transient A: order05/start05/cnt05)
    k_segmean<<<gpts, 256, 0, stream>>>(pc, order05, inv05, start05, cnt05, mean05, n);
    k_segmx<<<gpts, 256, 0, stream>>>(pc, order05, inv05, start05, cnt05, mean05,
                                      w05, b05, ww05, wb05, 512.f, 512.f, 64.f, mx05, n);
    // scale-1: mean + mx  (transient B overwrites transient A from here)
    k_segmean<<<gpts, 256, 0, stream>>>(pc, order1, inv1, start1, cnt1, mean1, n);
    k_segmx<<<gpts, 256, 0, stream>>>(pc, order1, inv1, start1, cnt1, mean1,
                                      w1, b1, ww1, wb1, 256.f, 256.f, 32.f, mx1, n);
    // fused am/at/af + segmented max -> output rows
    k_agg2<<<gpts, 256, 0, stream>>>(pc, order1, inv1, inv05, start1, cnt1,
                                     mean05, mx05, mean1, mx1,
                                     w05, b05, ww05, wb05, w1, b1, ww1, wb1,
                                     am_w, am_b, at_w, at_b, af_w, af_b,
                                     outMaxF, n);
    // pad empty rows
    k_pad<<<gpts, 256, 0, stream>>>(outMaxF, outCoord, U1p, n);

    (void)n_in; (void)out_size;
}

// Round 4
// 946.237 us; speedup vs baseline: 11.6933x; 1.6151x over previous
//
#include <hip/hip_runtime.h>
#include <cstdint>
#include <cstdio>

// ---------------- device helpers ----------------

struct Coords { int xi, yi, zi; };

// EXACT replication of reference quantization (all f32 ops, truncating cast)
__device__ __forceinline__ Coords quantc(float x, float y, float z, float sx, float sy, float sz) {
    Coords c;
    c.xi = (int)(((x - 0.0f)  / 51.2f) * sx);
    c.yi = (int)(((y + 25.6f) / 51.2f) * sy);
    c.zi = (int)(((z + 2.0f)  / 6.4f)  * sz);
    return c;
}

__device__ __forceinline__ int batch_of(int i, const int* __restrict__ ind, int B) {
    int bt = 0;
    for (int b = 1; b < B; ++b) if (i >= ind[b]) bt = b;
    return bt;
}

// order-preserving float<->uint transform for atomicMax on signed floats
__device__ __forceinline__ unsigned f2o(float f) {
    unsigned u = __float_as_uint(f);
    return (u & 0x80000000u) ? ~u : (u | 0x80000000u);
}
__device__ __forceinline__ float o2f(unsigned u) {
    return (u & 0x80000000u) ? __uint_as_float(u ^ 0x80000000u) : __uint_as_float(~u);
}
#define NEG_O 0x007FFFFFu   // f2o(-inf)

// bf16 helpers (RTNE)
__device__ __forceinline__ unsigned short f2bf(float x) {
    unsigned u = __float_as_uint(x);
    unsigned r = (u + 0x7FFFu + ((u >> 16) & 1u)) >> 16;
    return (unsigned short)r;
}
__device__ __forceinline__ float bf2f(unsigned h) {
    return __uint_as_float(h << 16);
}

// x[16] = (feat@W.T + b) * (mean@Ww.T + wb);  mean6 out = [mm, gmm]
__device__ __forceinline__ void compute_x16(
    float px, float py, float pz, float pw,
    float mx_, float my_, float mz_, Coords c,
    const float* __restrict__ W, const float* __restrict__ Bv,
    const float* __restrict__ Ww, const float* __restrict__ Wb,
    float* __restrict__ x, float* __restrict__ mean6) {
    float gx = px - (((float)c.xi + 0.5f) * 0.2f + 0.0f);
    float gy = py - (((float)c.yi + 0.5f) * 0.2f + (-25.6f));
    float gz = pz - (((float)c.zi + 0.5f) * 0.2f + (-2.0f));
    float mmx = px - mx_, mmy = py - my_, mmz = pz - mz_;
    float feat[10] = {px, py, pz, pw, mmx, mmy, mmz, gx, gy, gz};
    float mean[6]  = {mmx, mmy, mmz, gx, gy, gz};
#pragma unroll
    for (int j = 0; j < 6; ++j) mean6[j] = mean[j];
#pragma unroll
    for (int o = 0; o < 16; ++o) {
        float a = Bv[o];
#pragma unroll
        for (int j = 0; j < 10; ++j) a += feat[j] * W[o * 10 + j];
        float g = Wb[o];
#pragma unroll
        for (int j = 0; j < 6; ++j) g += mean[j] * Ww[o * 6 + j];
        x[o] = a * g;
    }
}

// ---------------- bitmask unique-rank machinery ----------------

__global__ __launch_bounds__(256) void k_bits(
    const float4* __restrict__ pc, const int* __restrict__ ind, int B, int n,
    unsigned* __restrict__ mask05, unsigned* __restrict__ mask1) {
    int i = blockIdx.x * 256 + threadIdx.x;
    if (i >= n) return;
    float4 p = pc[i];
    int bt = batch_of(i, ind, B);
    Coords c05 = quantc(p.x, p.y, p.z, 512.f, 512.f, 64.f);
    Coords c1  = quantc(p.x, p.y, p.z, 256.f, 256.f, 32.f);
    int lid05 = ((bt * 512 + c05.xi) * 512 + c05.yi) * 64 + c05.zi;
    int lid1  = ((bt * 256 + c1.xi)  * 256 + c1.yi)  * 32 + c1.zi;
    atomicOr(&mask05[lid05 >> 5], 1u << (lid05 & 31));
    atomicOr(&mask1[lid1 >> 5],  1u << (lid1 & 31));
}

__global__ __launch_bounds__(256) void k_chunk(
    const unsigned* __restrict__ mask, unsigned* __restrict__ bsum, int nWords) {
    int t = threadIdx.x;
    int base = blockIdx.x * 2048 + t;
    unsigned tot = 0;
#pragma unroll
    for (int k = 0; k < 8; ++k) {
        int w = base + k * 256;
        if (w < nWords) tot += __popc(mask[w]);
    }
    __shared__ unsigned s[256];
    s[t] = tot;
    __syncthreads();
    for (int off = 128; off > 0; off >>= 1) {
        if (t < off) s[t] += s[t + off];
        __syncthreads();
    }
    if (t == 0) bsum[blockIdx.x] = s[0];
}

__global__ __launch_bounds__(256) void k_chunku(
    const unsigned* __restrict__ val, unsigned* __restrict__ bsum, int nElem) {
    int t = threadIdx.x;
    int base = blockIdx.x * 2048 + t;
    unsigned tot = 0;
#pragma unroll
    for (int k = 0; k < 8; ++k) {
        int w = base + k * 256;
        if (w < nElem) tot += val[w];
    }
    __shared__ unsigned s[256];
    s[t] = tot;
    __syncthreads();
    for (int off = 128; off > 0; off >>= 1) {
        if (t < off) s[t] += s[t + off];
        __syncthreads();
    }
    if (t == 0) bsum[blockIdx.x] = s[0];
}

__global__ __launch_bounds__(1024) void k_scan(
    const unsigned* __restrict__ bsum, unsigned* __restrict__ bpref,
    unsigned* __restrict__ Uout, int nB) {
    __shared__ unsigned s[1024];
    int t = threadIdx.x;
    int ipt = (nB + 1023) >> 10;
    unsigned tot = 0;
    for (int k = 0; k < ipt; ++k) {
        int e = t * ipt + k;
        if (e < nB) tot += bsum[e];
    }
    s[t] = tot;
    __syncthreads();
    for (int off = 1; off < 1024; off <<= 1) {
        unsigned v = 0;
        if (t >= off) v = s[t - off];
        __syncthreads();
        if (t >= off) s[t] += v;
        __syncthreads();
    }
    unsigned run = s[t] - tot;  // exclusive
    for (int k = 0; k < ipt; ++k) {
        int e = t * ipt + k;
        if (e < nB) { bpref[e] = run; run += bsum[e]; }
    }
    if (t == 1023 && Uout) *Uout = s[1023];
}

__global__ __launch_bounds__(256) void k_wpref(
    const unsigned* __restrict__ mask, const unsigned* __restrict__ bpref,
    unsigned* __restrict__ wpref, int nWords) {
    int t = threadIdx.x;
    int base = blockIdx.x * 2048 + t * 8;
    unsigned p[8];
    unsigned tot = 0;
#pragma unroll
    for (int k = 0; k < 8; ++k) {
        int w = base + k;
        p[k] = (w < nWords) ? __popc(mask[w]) : 0u;
        tot += p[k];
    }
    __shared__ unsigned s[256];
    s[t] = tot;
    __syncthreads();
    for (int off = 1; off < 256; off <<= 1) {
        unsigned v = 0;
        if (t >= off) v = s[t - off];
        __syncthreads();
        if (t >= off) s[t] += v;
        __syncthreads();
    }
    unsigned run = bpref[blockIdx.x] + (s[t] - tot);
#pragma unroll
    for (int k = 0; k < 8; ++k) {
        int w = base + k;
        if (w < nWords) { wpref[w] = run; run += p[k]; }
    }
}

__global__ __launch_bounds__(256) void k_eprefu(
    const unsigned* __restrict__ val, const unsigned* __restrict__ bpref,
    unsigned* __restrict__ epref, int nElem) {
    int t = threadIdx.x;
    int base = blockIdx.x * 2048 + t * 8;
    unsigned p[8];
    unsigned tot = 0;
#pragma unroll
    for (int k = 0; k < 8; ++k) {
        int w = base + k;
        p[k] = (w < nElem) ? val[w] : 0u;
        tot += p[k];
    }
    __shared__ unsigned s[256];
    s[t] = tot;
    __syncthreads();
    for (int off = 1; off < 256; off <<= 1) {
        unsigned v = 0;
        if (t >= off) v = s[t - off];
        __syncthreads();
        if (t >= off) s[t] += v;
        __syncthreads();
    }
    unsigned run = bpref[blockIdx.x] + (s[t] - tot);
#pragma unroll
    for (int k = 0; k < 8; ++k) {
        int w = base + k;
        if (w < nElem) { epref[w] = run; run += p[k]; }
    }
}

// ---------------- point passes ----------------

__global__ __launch_bounds__(256) void k_rank(
    const float4* __restrict__ pc, const int* __restrict__ ind, int B, int n,
    const unsigned* __restrict__ mask05, const unsigned* __restrict__ wp05,
    const unsigned* __restrict__ mask1, const unsigned* __restrict__ wp1,
    unsigned* __restrict__ inv05, unsigned* __restrict__ inv1,
    unsigned* __restrict__ cnt05, unsigned* __restrict__ cnt1,
    unsigned* __restrict__ slot05, unsigned* __restrict__ slot1,
    float* __restrict__ outCoord, float* __restrict__ outInv) {
    int i = blockIdx.x * 256 + threadIdx.x;
    if (i >= n) return;
    float4 p = pc[i];
    int bt = batch_of(i, ind, B);
    Coords c05 = quantc(p.x, p.y, p.z, 512.f, 512.f, 64.f);
    Coords c1  = quantc(p.x, p.y, p.z, 256.f, 256.f, 32.f);
    int lid05 = ((bt * 512 + c05.xi) * 512 + c05.yi) * 64 + c05.zi;
    int lid1  = ((bt * 256 + c1.xi)  * 256 + c1.yi)  * 32 + c1.zi;

    unsigned w = (unsigned)lid05 >> 5, b = (unsigned)lid05 & 31u;
    unsigned r05 = wp05[w] + __popc(mask05[w] & ((1u << b) - 1u));
    w = (unsigned)lid1 >> 5; b = (unsigned)lid1 & 31u;
    unsigned r1 = wp1[w] + __popc(mask1[w] & ((1u << b) - 1u));

    inv05[i] = r05;
    inv1[i] = r1;
    outInv[i] = (float)r1;
    ((float4*)outCoord)[r1] = make_float4((float)bt, (float)c1.xi, (float)c1.yi, (float)c1.zi);

    slot05[i] = atomicAdd(&cnt05[r05], 1u);
    slot1[i]  = atomicAdd(&cnt1[r1], 1u);
}

// counting-sort scatter of {point, rank[,rank05]} records into CSR order
__global__ __launch_bounds__(256) void k_slot(
    const unsigned* __restrict__ inv05, const unsigned* __restrict__ inv1,
    const unsigned* __restrict__ slot05, const unsigned* __restrict__ slot1,
    const unsigned* __restrict__ start05, const unsigned* __restrict__ start1,
    unsigned* __restrict__ rec05 /*uint2*/, unsigned* __restrict__ rec1 /*uint4*/, int n) {
    int i = blockIdx.x * 256 + threadIdx.x;
    if (i >= n) return;
    unsigned r05 = inv05[i], r1 = inv1[i];
    unsigned p05 = start05[r05] + slot05[i];
    unsigned p1  = start1[r1] + slot1[i];
    ((uint2*)rec05)[p05] = make_uint2((unsigned)i, r05);
    ((uint4*)rec1)[p1]   = make_uint4((unsigned)i, r1, r05, 0u);
}

// wave-level segmented sum of xyz over CSR order -> per-voxel mean (owner writes)
__global__ __launch_bounds__(256) void k_segmean(
    const float4* __restrict__ pc,
    const unsigned* __restrict__ rec, int stride,
    const unsigned* __restrict__ start, const unsigned* __restrict__ cnt,
    float4* __restrict__ meanOut, int n) {
    int j = blockIdx.x * 256 + threadIdx.x;
    int lane = threadIdx.x & 63;
    bool live = j < n;
    unsigned r = 0xFFFFFFFFu;
    float sx = 0.f, sy = 0.f, sz = 0.f;
    if (live) {
        unsigned pi = rec[(size_t)j * stride];
        r = rec[(size_t)j * stride + 1];
        float4 p = pc[pi];
        sx = p.x; sy = p.y; sz = p.z;
    }
#pragma unroll
    for (int d = 1; d < 64; d <<= 1) {
        unsigned rn = (unsigned)__shfl_down((int)r, d);
        float ax = __shfl_down(sx, d);
        float ay = __shfl_down(sy, d);
        float az = __shfl_down(sz, d);
        bool ok = (lane + d) < 64 && rn == r;
        if (ok) { sx += ax; sy += ay; sz += az; }
    }
    if (!live) return;
    if (j != (int)start[r]) return;
    unsigned c = cnt[r];
    unsigned end = j + c;
    unsigned waveEnd = ((unsigned)j & ~63u) + 64u;
    for (unsigned j2 = waveEnd; j2 < end; ++j2) {
        float4 q = pc[rec[(size_t)j2 * stride]];
        sx += q.x; sy += q.y; sz += q.z;
    }
    float cf = (float)c;
    meanOut[r] = make_float4(sx / cf, sy / cf, sz / cf, 0.f);
}

// block-level LDS segmented max of x16 over CSR order -> per-voxel mx (bf16, owner writes)
__global__ __launch_bounds__(256) void k_segmx(
    const float4* __restrict__ pc,
    const unsigned* __restrict__ rec, int stride,
    const unsigned* __restrict__ start, const unsigned* __restrict__ cnt,
    const float4* __restrict__ meanIn,
    const float* __restrict__ W, const float* __restrict__ Bv,
    const float* __restrict__ Ww, const float* __restrict__ Wb,
    float sx_, float sy_, float sz_,
    unsigned short* __restrict__ mxOut, int n) {
    __shared__ float buf[256][17];
    int t = threadIdx.x;
    int j = blockIdx.x * 256 + t;
    bool live = j < n;
    unsigned r = 0;
    float x[16], d6[6];
    if (live) {
        unsigned pi = rec[(size_t)j * stride];
        r = rec[(size_t)j * stride + 1];
        float4 p = pc[pi];
        float4 mv = meanIn[r];
        Coords cc = quantc(p.x, p.y, p.z, sx_, sy_, sz_);
        compute_x16(p.x, p.y, p.z, p.w, mv.x, mv.y, mv.z, cc, W, Bv, Ww, Wb, x, d6);
    } else {
#pragma unroll
        for (int o = 0; o < 16; ++o) x[o] = 0.f;
    }
#pragma unroll
    for (int o = 0; o < 16; ++o) buf[t][o] = x[o];
    __syncthreads();
    if (!live || j != (int)start[r]) return;
    unsigned c = cnt[r];
    unsigned end = j + c;
    unsigned blockEnd = ((unsigned)blockIdx.x + 1u) * 256u;
    unsigned inEnd = end < blockEnd ? end : blockEnd;
    for (unsigned j2 = j + 1; j2 < inEnd; ++j2) {
        int t2 = t + (int)(j2 - (unsigned)j);
#pragma unroll
        for (int o = 0; o < 16; ++o) x[o] = fmaxf(x[o], buf[t2][o]);
    }
    float4 mv = meanIn[r];
    for (unsigned j2 = blockEnd; j2 < end; ++j2) {
        float4 q = pc[rec[(size_t)j2 * stride]];
        Coords cc = quantc(q.x, q.y, q.z, sx_, sy_, sz_);
        float x2[16];
        compute_x16(q.x, q.y, q.z, q.w, mv.x, mv.y, mv.z, cc, W, Bv, Ww, Wb, x2, d6);
#pragma unroll
        for (int o = 0; o < 16; ++o) x[o] = fmaxf(x[o], x2[o]);
    }
    unsigned pk[8];
#pragma unroll
    for (int k = 0; k < 8; ++k)
        pk[k] = (unsigned)f2bf(x[2 * k]) | ((unsigned)f2bf(x[2 * k + 1]) << 16);
    uint4* mr = (uint4*)(mxOut + (size_t)r * 16);
    mr[0] = make_uint4(pk[0], pk[1], pk[2], pk[3]);
    mr[1] = make_uint4(pk[4], pk[5], pk[6], pk[7]);
}

// pre-pass: flag segments crossing a 256-block boundary; init their out rows for atomicMax
__global__ __launch_bounds__(256) void k_binit(
    const unsigned* __restrict__ rec1, const unsigned* __restrict__ start1,
    unsigned char* __restrict__ flags, unsigned* __restrict__ outMaxU, int n, int nb) {
    int b = blockIdx.x * 256 + threadIdx.x + 1;
    if (b >= nb) return;
    int j = b * 256;
    if (j >= n) return;
    unsigned r = rec1[(size_t)j * 4 + 1];
    if (start1[r] < (unsigned)j) {
        flags[r] = 1;
        unsigned* row = outMaxU + (size_t)r * 32;
#pragma unroll
        for (int o = 0; o < 32; ++o) row[o] = NEG_O;
    }
}

// fused per-point pipeline + in-block segmented max.
// Interior segments: LDS merge, owner writes plain float row (coalesced).
// Boundary segments (~0.5%): 32 atomicMax (f2o) per point, untransformed by k_fin.
__global__ __launch_bounds__(256, 3) void k_val(
    const float4* __restrict__ pc,
    const unsigned* __restrict__ rec1,
    const unsigned* __restrict__ start1, const unsigned* __restrict__ cnt1,
    const float4* __restrict__ mean05, const unsigned short* __restrict__ mx05,
    const float4* __restrict__ mean1, const unsigned short* __restrict__ mx1,
    const float* __restrict__ w05, const float* __restrict__ b05,
    const float* __restrict__ ww05, const float* __restrict__ wb05,
    const float* __restrict__ w1g, const float* __restrict__ b1g,
    const float* __restrict__ ww1, const float* __restrict__ wb1,
    const float* __restrict__ am_w, const float* __restrict__ am_b,
    const float* __restrict__ at_w, const float* __restrict__ at_b,
    const float* __restrict__ af_w, const float* __restrict__ af_b,
    float* __restrict__ outMax, int n) {
    __shared__ float buf[256][33];
    int t = threadIdx.x;
    int j = blockIdx.x * 256 + t;
    bool live = j < n;
    float val[32];
    unsigned r = 0, s = 0;
    bool bound = false;
    if (live) {
        uint4 rc = ((const uint4*)rec1)[j];
        float4 p = pc[rc.x];
        r = rc.y;
        unsigned r05 = rc.z;
        s = start1[r];
        unsigned c = cnt1[r];
        bound = (s >> 8) != ((s + c - 1) >> 8);

        float at[32];
#pragma unroll
        for (int o = 0; o < 32; ++o) at[o] = at_b[o];

        float v16[16];
        // mx1 row (bf16) -> cols 48..63
        {
            const uint4* m4 = (const uint4*)(mx1 + (size_t)r * 16);
            uint4 a = m4[0], b2 = m4[1];
            unsigned pw[8] = {a.x, a.y, a.z, a.w, b2.x, b2.y, b2.z, b2.w};
#pragma unroll
            for (int k = 0; k < 8; ++k) {
                v16[2 * k] = bf2f(pw[k] & 0xFFFFu);
                v16[2 * k + 1] = bf2f(pw[k] >> 16);
            }
#pragma unroll
            for (int o = 0; o < 32; ++o) {
                float acc = 0.f;
#pragma unroll
                for (int jj = 0; jj < 16; ++jj) acc += v16[jj] * at_w[o * 64 + 48 + jj];
                at[o] += acc;
            }
        }
        // mx05 row (bf16) -> cols 16..31
        {
            const uint4* m4 = (const uint4*)(mx05 + (size_t)r05 * 16);
            uint4 a = m4[0], b2 = m4[1];
            unsigned pw[8] = {a.x, a.y, a.z, a.w, b2.x, b2.y, b2.z, b2.w};
#pragma unroll
            for (int k = 0; k < 8; ++k) {
                v16[2 * k] = bf2f(pw[k] & 0xFFFFu);
                v16[2 * k + 1] = bf2f(pw[k] >> 16);
            }
#pragma unroll
            for (int o = 0; o < 32; ++o) {
                float acc = 0.f;
#pragma unroll
                for (int jj = 0; jj < 16; ++jj) acc += v16[jj] * at_w[o * 64 + 16 + jj];
                at[o] += acc;
            }
        }
        float mean6[6], d6[6];
        // x05 -> cols 0..15
        {
            float4 mv = mean05[r05];
            Coords cc = quantc(p.x, p.y, p.z, 512.f, 512.f, 64.f);
            compute_x16(p.x, p.y, p.z, p.w, mv.x, mv.y, mv.z, cc, w05, b05, ww05, wb05, v16, d6);
#pragma unroll
            for (int o = 0; o < 32; ++o) {
                float acc = 0.f;
#pragma unroll
                for (int jj = 0; jj < 16; ++jj) acc += v16[jj] * at_w[o * 64 + jj];
                at[o] += acc;
            }
        }
        // x1 -> cols 32..47 (keeps mean6)
        {
            float4 mv = mean1[r];
            Coords cc = quantc(p.x, p.y, p.z, 256.f, 256.f, 32.f);
            compute_x16(p.x, p.y, p.z, p.w, mv.x, mv.y, mv.z, cc, w1g, b1g, ww1, wb1, v16, mean6);
#pragma unroll
            for (int o = 0; o < 32; ++o) {
                float acc = 0.f;
#pragma unroll
                for (int jj = 0; jj < 16; ++jj) acc += v16[jj] * at_w[o * 64 + 32 + jj];
                at[o] += acc;
            }
        }
        // h = relu(am)*relu(at), in place
#pragma unroll
        for (int o = 0; o < 32; ++o) {
            float am = am_b[o];
#pragma unroll
            for (int jj = 0; jj < 6; ++jj) am += mean6[jj] * am_w[o * 6 + jj];
            at[o] = fmaxf(am, 0.f) * fmaxf(at[o], 0.f);
        }
        // val = h @ af_w.T + af_b
#pragma unroll
        for (int o = 0; o < 32; ++o) {
            float v = af_b[o];
#pragma unroll
            for (int jj = 0; jj < 32; ++jj) v += at[jj] * af_w[o * 32 + jj];
            val[o] = v;
        }
        if (bound) {
            unsigned* row = (unsigned*)outMax + (size_t)r * 32;
#pragma unroll
            for (int o = 0; o < 32; ++o) atomicMax(&row[o], f2o(val[o]));
        }
    } else {
#pragma unroll
        for (int o = 0; o < 32; ++o) val[o] = 0.f;
    }
#pragma unroll
    for (int o = 0; o < 32; ++o) buf[t][o] = val[o];
    __syncthreads();
    if (!live || bound || j != (int)s) return;
    unsigned c = cnt1[r];
    unsigned end = s + c;   // interior: entirely inside this block
    for (unsigned j2 = (unsigned)j + 1; j2 < end; ++j2) {
        int t2 = t + (int)(j2 - (unsigned)j);
#pragma unroll
        for (int o = 0; o < 32; ++o) val[o] = fmaxf(val[o], buf[t2][o]);
    }
    float4* ov = (float4*)(outMax + (size_t)r * 32);
#pragma unroll
    for (int k = 0; k < 8; ++k)
        ov[k] = make_float4(val[4 * k], val[4 * k + 1], val[4 * k + 2], val[4 * k + 3]);
}

// untransform boundary rows; zero pad rows (maxf + coords)
__global__ __launch_bounds__(256) void k_fin(
    float* __restrict__ outMax, float* __restrict__ outCoord,
    const unsigned char* __restrict__ flags, const unsigned* __restrict__ U1p, int n) {
    int idx = blockIdx.x * 256 + threadIdx.x;
    if (idx >= n * 32) return;
    int r = idx >> 5, o = idx & 31;
    unsigned U = *U1p;
    if ((unsigned)r >= U) {
        outMax[idx] = 0.f;
        if (o < 4) outCoord[r * 4 + o] = 0.f;
    } else if (flags[r]) {
        outMax[idx] = o2f(((const unsigned*)outMax)[idx]);
    }
}

// ---------------- host launch ----------------

extern "C" void kernel_launch(void* const* d_in, const int* in_sizes, int n_in,
                              void* d_out, int out_size, void* d_ws, size_t ws_size,
                              hipStream_t stream) {
    const float4* pc = (const float4*)d_in[0];
    const int* ind   = (const int*)d_in[1];
    const float* w05 = (const float*)d_in[2];
    const float* b05 = (const float*)d_in[3];
    const float* ww05 = (const float*)d_in[4];
    const float* wb05 = (const float*)d_in[5];
    const float* w1  = (const float*)d_in[6];
    const float* b1  = (const float*)d_in[7];
    const float* ww1 = (const float*)d_in[8];
    const float* wb1 = (const float*)d_in[9];
    const float* am_w = (const float*)d_in[10];
    const float* am_b = (const float*)d_in[11];
    const float* at_w = (const float*)d_in[12];
    const float* at_b = (const float*)d_in[13];
    const float* af_w = (const float*)d_in[14];
    const float* af_b = (const float*)d_in[15];

    int n = in_sizes[0] / 4;
    int B = in_sizes[1] - 1;

    int nW05 = B * (512 * 512 * 64 / 32);
    int nW1  = B * (256 * 256 * 32 / 32);
    int nB05 = (nW05 + 2047) / 2048;
    int nB1  = (nW1 + 2047) / 2048;
    int nCh  = (n + 2047) / 2048;

    size_t off = 0;
    char* base = (char*)d_ws;
    auto take = [&](size_t bytes) -> char* {
        char* p = base + off;
        off = (off + bytes + 255) & ~(size_t)255;
        return p;
    };

    // zero-init group (single contiguous memset)
    unsigned* mask05 = (unsigned*)take((size_t)nW05 * 4);
    unsigned* mask1  = (unsigned*)take((size_t)nW1 * 4);
    unsigned* cnt05  = (unsigned*)take((size_t)n * 4);
    unsigned* cnt1   = (unsigned*)take((size_t)n * 4);
    unsigned char* flags = (unsigned char*)take((size_t)n);
    size_t zeroBytes = off;

    unsigned* wp05   = (unsigned*)take((size_t)nW05 * 4);
    unsigned* wp1    = (unsigned*)take((size_t)nW1 * 4);
    unsigned* inv05  = (unsigned*)take((size_t)n * 4);
    unsigned* inv1   = (unsigned*)take((size_t)n * 4);
    unsigned* slot05 = (unsigned*)take((size_t)n * 4);
    unsigned* slot1  = (unsigned*)take((size_t)n * 4);
    unsigned* start05 = (unsigned*)take((size_t)n * 4);
    unsigned* start1  = (unsigned*)take((size_t)n * 4);
    unsigned* rec05   = (unsigned*)take((size_t)n * 8);   // uint2 {i, r05}
    unsigned* rec1    = (unsigned*)take((size_t)n * 16);  // uint4 {i, r1, r05, 0}
    float4*   mean05  = (float4*)take((size_t)n * 16);
    float4*   mean1   = (float4*)take((size_t)n * 16);
    unsigned short* mx05 = (unsigned short*)take((size_t)n * 32);  // bf16 [n][16]
    unsigned short* mx1  = (unsigned short*)take((size_t)n * 32);
    unsigned* bsum05  = (unsigned*)take((size_t)nB05 * 4);
    unsigned* bpref05 = (unsigned*)take((size_t)nB05 * 4);
    unsigned* bsum1   = (unsigned*)take((size_t)nB1 * 4);
    unsigned* bpref1  = (unsigned*)take((size_t)nB1 * 4);
    unsigned* bsC05   = (unsigned*)take((size_t)nCh * 4);
    unsigned* bpC05   = (unsigned*)take((size_t)nCh * 4);
    unsigned* bsC1    = (unsigned*)take((size_t)nCh * 4);
    unsigned* bpC1    = (unsigned*)take((size_t)nCh * 4);
    unsigned* U1p     = (unsigned*)take(4);
    size_t total = off;

    if (ws_size < total) {
        fprintf(stderr, "kernel_launch: ws too small (%zu < %zu)\n", ws_size, total);
        return;
    }

    float* outMaxF = (float*)d_out;                      // [n,32]
    float* outCoord = (float*)d_out + (size_t)n * 32;    // [n,4]
    float* outInv = (float*)d_out + (size_t)n * 36;      // [n]

    hipMemsetAsync(d_ws, 0, zeroBytes, stream);

    int gpts = (n + 255) / 256;
    // unique-rank machinery
    k_bits<<<gpts, 256, 0, stream>>>(pc, ind, B, n, mask05, mask1);
    k_chunk<<<nB05, 256, 0, stream>>>(mask05, bsum05, nW05);
    k_chunk<<<nB1, 256, 0, stream>>>(mask1, bsum1, nW1);
    k_scan<<<1, 1024, 0, stream>>>(bsum05, bpref05, nullptr, nB05);
    k_scan<<<1, 1024, 0, stream>>>(bsum1, bpref1, U1p, nB1);
    k_wpref<<<nB05, 256, 0, stream>>>(mask05, bpref05, wp05, nW05);
    k_wpref<<<nB1, 256, 0, stream>>>(mask1, bpref1, wp1, nW1);
    // ranks + counts + slots
    k_rank<<<gpts, 256, 0, stream>>>(pc, ind, B, n, mask05, wp05, mask1, wp1,
                                     inv05, inv1, cnt05, cnt1, slot05, slot1,
                                     outCoord, outInv);
    // CSR starts
    k_chunku<<<nCh, 256, 0, stream>>>(cnt05, bsC05, n);
    k_chunku<<<nCh, 256, 0, stream>>>(cnt1, bsC1, n);
    k_scan<<<1, 1024, 0, stream>>>(bsC05, bpC05, nullptr, nCh);
    k_scan<<<1, 1024, 0, stream>>>(bsC1, bpC1, nullptr, nCh);
    k_eprefu<<<nCh, 256, 0, stream>>>(cnt05, bpC05, start05, n);
    k_eprefu<<<nCh, 256, 0, stream>>>(cnt1, bpC1, start1, n);
    // counting-sort scatter of records
    k_slot<<<gpts, 256, 0, stream>>>(inv05, inv1, slot05, slot1,
                                     start05, start1, rec05, rec1, n);
    // boundary-segment flags + row init (needs rec1 + start1)
    k_binit<<<(gpts + 255) / 256, 256, 0, stream>>>(rec1, start1, flags,
                                                    (unsigned*)outMaxF, n, gpts);
    // per-voxel means + mx (bf16)
    k_segmean<<<gpts, 256, 0, stream>>>(pc, rec05, 2, start05, cnt05, mean05, n);
    k_segmx<<<gpts, 256, 0, stream>>>(pc, rec05, 2, start05, cnt05, mean05,
                                      w05, b05, ww05, wb05, 512.f, 512.f, 64.f, mx05, n);
    k_segmean<<<gpts, 256, 0, stream>>>(pc, rec1, 4, start1, cnt1, mean1, n);
    k_segmx<<<gpts, 256, 0, stream>>>(pc, rec1, 4, start1, cnt1, mean1,
                                      w1, b1, ww1, wb1, 256.f, 256.f, 32.f, mx1, n);
    // fused pipeline + segmented max
    k_val<<<gpts, 256, 0, stream>>>(pc, rec1, start1, cnt1,
                                    mean05, mx05, mean1, mx1,
                                    w05, b05, ww05, wb05, w1, b1, ww1, wb1,
                                    am_w, am_b, at_w, at_b, af_w, af_b,
                                    outMaxF, n);
    // untransform boundary rows + zero pad rows
    k_fin<<<(n * 32 + 255) / 256, 256, 0, stream>>>(outMaxF, outCoord, flags, U1p, n);

    (void)n_in; (void)out_size;
}